// Round 2
// baseline (23240.535 us; speedup 1.0000x reference)
//
#include <hip/hip_runtime.h>

typedef __attribute__((ext_vector_type(8))) short short8;
typedef __attribute__((ext_vector_type(4))) float floatx4;

#define TT 512
#define BB 64
#define II 256
#define HH 2048
#define BH (BB * HH)

#define MFMA(a, b, c) __builtin_amdgcn_mfma_f32_16x16x32_bf16(a, b, c, 0, 0, 0)

__device__ __forceinline__ short f2bf(float f) {
  unsigned u = __builtin_bit_cast(unsigned, f);
  u = (u + 0x7fffu + ((u >> 16) & 1u)) >> 16;
  return (short)u;
}
__device__ __forceinline__ float bf2f(short s) {
  unsigned u = ((unsigned)(unsigned short)s) << 16;
  return __builtin_bit_cast(float, u);
}

// ---- pack W_hat [2048][2048] fp32 -> MFMA-B-fragment-ordered bf16 hi/lo ----
// PW[(ntile*64 + kblock)*64 + lane] = short8 of W[ntile*16 + (lane&15)][kblock*32 + (lane>>4)*8 + j]
__global__ __launch_bounds__(64) void pack_what(const float* __restrict__ What,
                                                short8* __restrict__ PWhi,
                                                short8* __restrict__ PWlo) {
  const int ntile = blockIdx.x >> 6;
  const int kb = blockIdx.x & 63;
  const int L = threadIdx.x;
  const int lm = L & 15, lq = L >> 4;
  const float* p = What + (size_t)(ntile * 16 + lm) * HH + kb * 32 + lq * 8;
  short8 hi, lo;
#pragma unroll
  for (int j = 0; j < 8; ++j) {
    float f = p[j];
    short h = f2bf(f);
    hi[j] = h;
    lo[j] = f2bf(f - bf2f(h));
  }
  const size_t o = (size_t)blockIdx.x * 64 + L;
  PWhi[o] = hi;
  PWlo[o] = lo;
}

// ---- initial state -> bf16 hi/lo slot0; zero barrier counter ----
__global__ __launch_bounds__(256) void prep_state(const float* __restrict__ s0,
                                                  short* __restrict__ Shi,
                                                  short* __restrict__ Slo,
                                                  unsigned* __restrict__ flags) {
  int i = blockIdx.x * 256 + threadIdx.x;  // 131072 total
  if (i < 64) flags[i] = 0;
  float f = s0[i];
  short h = f2bf(f);
  Shi[i] = h;
  Slo[i] = f2bf(f - bf2f(h));
}

// ---- u = X @ Win^T into d_out (verified round-2 kernel, unchanged) ----
__global__ __launch_bounds__(256) void ugemm(const float* __restrict__ X,
                                             const float* __restrict__ Win,
                                             float* __restrict__ U) {
  const int w = threadIdx.x >> 6;
  const int L = threadIdx.x & 63;
  const int lm = L & 15, lq = L >> 4;
  const int m0 = blockIdx.x * 128 + (w >> 1) * 64;
  const int n0 = blockIdx.y * 64 + (w & 1) * 32;

  short8 Bhi[2][8], Blo[2][8];
#pragma unroll
  for (int nt = 0; nt < 2; ++nt)
#pragma unroll
    for (int kt = 0; kt < 8; ++kt) {
      const float* p = Win + (n0 + nt * 16 + lm) * II + kt * 32 + lq * 8;
      short8 hi, lo;
#pragma unroll
      for (int j = 0; j < 8; ++j) {
        float f = p[j];
        short h = f2bf(f);
        hi[j] = h;
        lo[j] = f2bf(f - bf2f(h));
      }
      Bhi[nt][kt] = hi;
      Blo[nt][kt] = lo;
    }

#pragma unroll 1
  for (int mt = 0; mt < 4; ++mt) {
    short8 Ahi[8], Alo[8];
    const int r = m0 + mt * 16 + lm;
#pragma unroll
    for (int kt = 0; kt < 8; ++kt) {
      const float* p = X + (size_t)r * II + kt * 32 + lq * 8;
      short8 hi, lo;
#pragma unroll
      for (int j = 0; j < 8; ++j) {
        float f = p[j];
        short h = f2bf(f);
        hi[j] = h;
        lo[j] = f2bf(f - bf2f(h));
      }
      Ahi[kt] = hi;
      Alo[kt] = lo;
    }
#pragma unroll
    for (int nt = 0; nt < 2; ++nt) {
      floatx4 acc = {0.f, 0.f, 0.f, 0.f};
#pragma unroll
      for (int kt = 0; kt < 8; ++kt) {
        acc = MFMA(Ahi[kt], Bhi[nt][kt], acc);
        acc = MFMA(Ahi[kt], Blo[nt][kt], acc);
        acc = MFMA(Alo[kt], Bhi[nt][kt], acc);
      }
#pragma unroll
      for (int rr = 0; rr < 4; ++rr) {
        int row = m0 + mt * 16 + lq * 4 + rr;
        int col = n0 + nt * 16 + lm;
        U[(size_t)row * HH + col] = acc[rr];
      }
    }
  }
}

// ---- persistent recurrence: all 512 steps in one cooperative launch ----
// 256 blocks x 256 thr, 1 block/CU. block = (mhalf: 32 rows, ntile: 16 cols),
// 4 waves k-split (512 each). Each wave holds its W slice in 128 VGPRs for the
// whole kernel (asm keep-alive forbids rematerialization). Triple-buffered
// state -> 1 grid barrier per step. Barrier = single monotonic counter:
// relaxed same-line polling (1 txn/wave/poll), fences only at arrival/exit.
__global__ __launch_bounds__(256, 1) void recurrence(
    const short8* __restrict__ PWhi, const short8* __restrict__ PWlo,
    short* __restrict__ SH, short* __restrict__ SL,
    float* __restrict__ out, unsigned* __restrict__ flags) {
  __shared__ float red[4][32][17];
  const int tid = threadIdx.x;
  const int w = tid >> 6;
  const int L = tid & 63;
  const int lm = L & 15, lq = L >> 4;
  const int mhalf = blockIdx.x & 1;
  const int ntile = blockIdx.x >> 1;  // 0..127
  const int mbase = mhalf * 32;
  const int kw = w * 512;

  // W fragments -> registers, ONCE. 16 kt x (hi,lo) x 4 VGPR = 128 VGPR.
  // asm keep-alive: values become asm-defined => compiler cannot re-load
  // them from memory inside the t-loop (the round-1 VGPR_Count=112 showed
  // it was rematerializing these loads every step).
  short8 Wh[16], Wl[16];
  const size_t wb = ((size_t)ntile * 64 + (kw >> 5)) * 64 + L;
#pragma unroll
  for (int kt = 0; kt < 16; ++kt) {
    Wh[kt] = PWhi[wb + (size_t)kt * 64];
    Wl[kt] = PWlo[wb + (size_t)kt * 64];
  }
#pragma unroll
  for (int kt = 0; kt < 16; ++kt) {
    floatx4 th = __builtin_bit_cast(floatx4, Wh[kt]);
    floatx4 tl = __builtin_bit_cast(floatx4, Wl[kt]);
    asm volatile("" : "+v"(th), "+v"(tl));
    Wh[kt] = __builtin_bit_cast(short8, th);
    Wl[kt] = __builtin_bit_cast(short8, tl);
  }

  const int r0 = (mbase + lm) * HH;
  const int r1 = (mbase + 16 + lm) * HH;
  // epilogue: 2 outputs/thread
  const int ecol = tid & 15;
  const int e0row = tid >> 4;    // 0..15
  const int e1row = 16 + e0row;  // 16..31
  const int idx0 = (mbase + e0row) * HH + ntile * 16 + ecol;
  const int idx1 = (mbase + e1row) * HH + ntile * 16 + ecol;

  unsigned* cnt = flags;  // single monotonic arrival counter

  int slot = 0;
  for (int t = 0; t < TT; ++t) {
    int nslot = slot + 1;
    if (nslot == 3) nslot = 0;
    const short* curH = SH + slot * BH;
    const short* curL = SL + slot * BH;
    short* nxtH = SH + nslot * BH;
    short* nxtL = SL + nslot * BH;
    float* ot = out + (size_t)t * BH;

    // epilogue operands early (HBM u read hides under the k-loop)
    float u0 = ot[idx0], u1 = ot[idx1];
    float sp0 = bf2f(curH[idx0]) + bf2f(curL[idx0]);
    float sp1 = bf2f(curH[idx1]) + bf2f(curL[idx1]);

    // 6 accumulators: MFMA dependency distance 6
    floatx4 a00 = {0.f, 0.f, 0.f, 0.f}, a01 = a00, a02 = a00;
    floatx4 a10 = a00, a11 = a00, a12 = a00;
#pragma unroll
    for (int kt = 0; kt < 16; ++kt) {
      const int k0 = kw + kt * 32 + lq * 8;
      short8 x0h = *(const short8*)(curH + r0 + k0);
      short8 x0l = *(const short8*)(curL + r0 + k0);
      short8 x1h = *(const short8*)(curH + r1 + k0);
      short8 x1l = *(const short8*)(curL + r1 + k0);
      a00 = MFMA(x0h, Wh[kt], a00);
      a10 = MFMA(x1h, Wh[kt], a10);
      a01 = MFMA(x0h, Wl[kt], a01);
      a11 = MFMA(x1h, Wl[kt], a11);
      a02 = MFMA(x0l, Wh[kt], a02);
      a12 = MFMA(x1l, Wh[kt], a12);
    }
    floatx4 s0v = a00 + a01 + a02;
    floatx4 s1v = a10 + a11 + a12;

    // C layout: col = lane&15, row = (lane>>4)*4 + reg
#pragma unroll
    for (int r = 0; r < 4; ++r) {
      red[w][lq * 4 + r][lm] = s0v[r];
      red[w][16 + lq * 4 + r][lm] = s1v[r];
    }
    __syncthreads();

    float z0 = u0, z1 = u1;
#pragma unroll
    for (int ww = 0; ww < 4; ++ww) {
      z0 += red[ww][e0row][ecol];
      z1 += red[ww][e1row][ecol];
    }
    const float sn0 = 0.5f * (sp0 + tanhf(z0));
    const float sn1 = 0.5f * (sp1 + tanhf(z1));
    ot[idx0] = sn0;
    ot[idx1] = sn1;
    const short h0 = f2bf(sn0), h1 = f2bf(sn1);
    nxtH[idx0] = h0;
    nxtL[idx0] = f2bf(sn0 - bf2f(h0));
    nxtH[idx1] = h1;
    nxtL[idx1] = f2bf(sn1 - bf2f(h1));

    // ---- grid barrier (one per step; triple-buffer makes this sufficient) ----
    __syncthreads();  // drains this block's stores (vmcnt(0) before s_barrier)
    if (tid == 0) {
      __builtin_amdgcn_fence(__ATOMIC_RELEASE, "agent");  // L2 writeback
      __hip_atomic_fetch_add(cnt, 1u, __ATOMIC_RELAXED, __HIP_MEMORY_SCOPE_AGENT);
    }
    if (t != TT - 1) {
      const unsigned tgt = 256u * (unsigned)(t + 1);
      // all threads poll the SAME line: coalesces to 1 txn/wave/poll;
      // relaxed loads => no per-poll cache invalidation
      while (__hip_atomic_load(cnt, __ATOMIC_RELAXED, __HIP_MEMORY_SCOPE_AGENT) < tgt)
        __builtin_amdgcn_s_sleep(2);
      __builtin_amdgcn_fence(__ATOMIC_ACQUIRE, "agent");  // invalidate stale lines
      __syncthreads();
    }

    slot = nslot;
  }
}

extern "C" void kernel_launch(void* const* d_in, const int* in_sizes, int n_in,
                              void* d_out, int out_size, void* d_ws, size_t ws_size,
                              hipStream_t stream) {
  const float* x = (const float*)d_in[0];     // [512,64,256]
  const float* s0 = (const float*)d_in[1];    // [64,2048]
  const float* Win = (const float*)d_in[2];   // [2048,256]
  const float* What = (const float*)d_in[3];  // [2048,2048]
  float* out = (float*)d_out;                 // [512,64,2048]

  short8* PWhi = (short8*)d_ws;                       // 8 MB
  short8* PWlo = PWhi + (size_t)HH * HH / 8;          // 8 MB
  short* SH = (short*)(PWlo + (size_t)HH * HH / 8);   // 3 slots x 256 KB
  short* SL = SH + 3 * BH;                            // 3 slots x 256 KB
  unsigned* flags = (unsigned*)(SL + 3 * BH);         // counter + pad

  pack_what<<<8192, 64, 0, stream>>>(What, PWhi, PWlo);
  prep_state<<<512, 256, 0, stream>>>(s0, SH, SL, flags);
  ugemm<<<dim3(256, 32), 256, 0, stream>>>(x, Win, out);

  void* kargs[] = {&PWhi, &PWlo, &SH, &SL, &out, &flags};
  hipError_t ce = hipLaunchCooperativeKernel(
      reinterpret_cast<void*>(&recurrence), dim3(256), dim3(256), kargs, 0, stream);
  if (ce != hipSuccess) {
    // fallback: plain launch (256 blocks on 256 CUs, 1 block/CU => co-resident)
    recurrence<<<256, 256, 0, stream>>>(PWhi, PWlo, SH, SL, out, flags);
  }
}

// Round 3
// 6280.344 us; speedup vs baseline: 3.7005x; 3.7005x over previous
//
#include <hip/hip_runtime.h>

typedef __attribute__((ext_vector_type(8))) short short8;
typedef __attribute__((ext_vector_type(4))) float floatx4;

#define TT 512
#define BB 64
#define II 256
#define HH 2048
#define BH (BB * HH)

#define MFMA(a, b, c) __builtin_amdgcn_mfma_f32_16x16x32_bf16(a, b, c, 0, 0, 0)

__device__ __forceinline__ short f2bf(float f) {
  unsigned u = __builtin_bit_cast(unsigned, f);
  u = (u + 0x7fffu + ((u >> 16) & 1u)) >> 16;
  return (short)u;
}
__device__ __forceinline__ float bf2f(short s) {
  unsigned u = ((unsigned)(unsigned short)s) << 16;
  return __builtin_bit_cast(float, u);
}

// ---- pack W_hat [2048][2048] fp32 -> MFMA-B-fragment-ordered bf16 hi/lo ----
// PW[(ntile*64 + kblock)*64 + lane] = short8 of W[ntile*16 + (lane&15)][kblock*32 + (lane>>4)*8 + j]
__global__ __launch_bounds__(64) void pack_what(const float* __restrict__ What,
                                                short8* __restrict__ PWhi,
                                                short8* __restrict__ PWlo) {
  const int ntile = blockIdx.x >> 6;
  const int kb = blockIdx.x & 63;
  const int L = threadIdx.x;
  const int lm = L & 15, lq = L >> 4;
  const float* p = What + (size_t)(ntile * 16 + lm) * HH + kb * 32 + lq * 8;
  short8 hi, lo;
#pragma unroll
  for (int j = 0; j < 8; ++j) {
    float f = p[j];
    short h = f2bf(f);
    hi[j] = h;
    lo[j] = f2bf(f - bf2f(h));
  }
  const size_t o = (size_t)blockIdx.x * 64 + L;
  PWhi[o] = hi;
  PWlo[o] = lo;
}

// ---- initial state -> bf16 hi/lo [64][2048] ----
__global__ __launch_bounds__(256) void prep_state(const float* __restrict__ s0,
                                                  short* __restrict__ Shi,
                                                  short* __restrict__ Slo) {
  int i = blockIdx.x * 256 + threadIdx.x;  // 131072 total
  float f = s0[i];
  short h = f2bf(f);
  Shi[i] = h;
  Slo[i] = f2bf(f - bf2f(h));
}

// ---- u = X @ Win^T into d_out (verified, unchanged) ----
__global__ __launch_bounds__(256) void ugemm(const float* __restrict__ X,
                                             const float* __restrict__ Win,
                                             float* __restrict__ U) {
  const int w = threadIdx.x >> 6;
  const int L = threadIdx.x & 63;
  const int lm = L & 15, lq = L >> 4;
  const int m0 = blockIdx.x * 128 + (w >> 1) * 64;
  const int n0 = blockIdx.y * 64 + (w & 1) * 32;

  short8 Bhi[2][8], Blo[2][8];
#pragma unroll
  for (int nt = 0; nt < 2; ++nt)
#pragma unroll
    for (int kt = 0; kt < 8; ++kt) {
      const float* p = Win + (n0 + nt * 16 + lm) * II + kt * 32 + lq * 8;
      short8 hi, lo;
#pragma unroll
      for (int j = 0; j < 8; ++j) {
        float f = p[j];
        short h = f2bf(f);
        hi[j] = h;
        lo[j] = f2bf(f - bf2f(h));
      }
      Bhi[nt][kt] = hi;
      Blo[nt][kt] = lo;
    }

#pragma unroll 1
  for (int mt = 0; mt < 4; ++mt) {
    short8 Ahi[8], Alo[8];
    const int r = m0 + mt * 16 + lm;
#pragma unroll
    for (int kt = 0; kt < 8; ++kt) {
      const float* p = X + (size_t)r * II + kt * 32 + lq * 8;
      short8 hi, lo;
#pragma unroll
      for (int j = 0; j < 8; ++j) {
        float f = p[j];
        short h = f2bf(f);
        hi[j] = h;
        lo[j] = f2bf(f - bf2f(h));
      }
      Ahi[kt] = hi;
      Alo[kt] = lo;
    }
#pragma unroll
    for (int nt = 0; nt < 2; ++nt) {
      floatx4 acc = {0.f, 0.f, 0.f, 0.f};
#pragma unroll
      for (int kt = 0; kt < 8; ++kt) {
        acc = MFMA(Ahi[kt], Bhi[nt][kt], acc);
        acc = MFMA(Ahi[kt], Blo[nt][kt], acc);
        acc = MFMA(Alo[kt], Bhi[nt][kt], acc);
      }
#pragma unroll
      for (int rr = 0; rr < 4; ++rr) {
        int row = m0 + mt * 16 + lq * 4 + rr;
        int col = n0 + nt * 16 + lm;
        U[(size_t)row * HH + col] = acc[rr];
      }
    }
  }
}

// ---- one recurrence step ----
// grid 256 blocks x 1024 thr (16 waves = 4 waves/SIMD for latency hiding).
// block = (mhalf: 32 b-rows, ntile: 16 h-cols). 16-wave k-split, 128 k each.
// W streamed from packed L2-resident frags (multi-launch keeps L2 warm:
// kernel boundaries do NOT invalidate L2, unlike agent-scope fences).
__global__ __launch_bounds__(1024, 4) void step_kernel(
    const short8* __restrict__ PWhi, const short8* __restrict__ PWlo,
    const short* __restrict__ Sh, const short* __restrict__ Sl,
    short* __restrict__ Nh, short* __restrict__ Nl,
    float* __restrict__ out_t) {
  __shared__ float red[16][32][17];
  const int tid = threadIdx.x;
  const int w = tid >> 6;       // 0..15
  const int L = tid & 63;
  const int lm = L & 15, lq = L >> 4;
  const int mhalf = blockIdx.x & 1;
  const int ntile = blockIdx.x >> 1;  // 0..127
  const int mbase = mhalf * 32;
  const int kw = w * 128;  // wave k-base

  // epilogue operands early (hide u HBM read + state re-read under k-loop)
  const int ecol = tid & 15;
  const int erow = tid >> 4;  // 0..31 for tid<512
  float u0 = 0.f, sp0 = 0.f;
  int idx0 = 0;
  if (tid < 512) {
    idx0 = (mbase + erow) * HH + ntile * 16 + ecol;
    u0 = out_t[idx0];
    sp0 = bf2f(Sh[idx0]) + bf2f(Sl[idx0]);
  }

  floatx4 a00 = {0.f, 0.f, 0.f, 0.f}, a01 = a00, a02 = a00;
  floatx4 a10 = a00, a11 = a00, a12 = a00;
  const size_t wbase = ((size_t)ntile * 64 + (kw >> 5)) * 64 + L;
  const int r0 = (mbase + lm) * HH;
  const int r1 = (mbase + 16 + lm) * HH;
#pragma unroll
  for (int kt = 0; kt < 4; ++kt) {
    short8 bh = PWhi[wbase + (size_t)kt * 64];
    short8 bl = PWlo[wbase + (size_t)kt * 64];
    const int k0 = kw + kt * 32 + lq * 8;
    short8 a0h = *(const short8*)(Sh + r0 + k0);
    short8 a0l = *(const short8*)(Sl + r0 + k0);
    short8 a1h = *(const short8*)(Sh + r1 + k0);
    short8 a1l = *(const short8*)(Sl + r1 + k0);
    a00 = MFMA(a0h, bh, a00);
    a10 = MFMA(a1h, bh, a10);
    a01 = MFMA(a0h, bl, a01);
    a11 = MFMA(a1h, bl, a11);
    a02 = MFMA(a0l, bh, a02);
    a12 = MFMA(a1l, bh, a12);
  }
  floatx4 s0v = a00 + a01 + a02;
  floatx4 s1v = a10 + a11 + a12;

  // C layout: col = lane&15 (n), row = (lane>>4)*4 + reg (m)
#pragma unroll
  for (int r = 0; r < 4; ++r) {
    red[w][lq * 4 + r][lm] = s0v[r];
    red[w][16 + lq * 4 + r][lm] = s1v[r];
  }
  __syncthreads();

  if (tid < 512) {
    float z = u0;
#pragma unroll
    for (int ww = 0; ww < 16; ++ww) z += red[ww][erow][ecol];
    const float sn = 0.5f * (sp0 + tanhf(z));
    out_t[idx0] = sn;
    const short shi = f2bf(sn);
    Nh[idx0] = shi;
    Nl[idx0] = f2bf(sn - bf2f(shi));
  }
}

extern "C" void kernel_launch(void* const* d_in, const int* in_sizes, int n_in,
                              void* d_out, int out_size, void* d_ws, size_t ws_size,
                              hipStream_t stream) {
  const float* x = (const float*)d_in[0];     // [512,64,256]
  const float* s0 = (const float*)d_in[1];    // [64,2048]
  const float* Win = (const float*)d_in[2];   // [2048,256]
  const float* What = (const float*)d_in[3];  // [2048,2048]
  float* out = (float*)d_out;                 // [512,64,2048]

  short8* PWhi = (short8*)d_ws;                       // 8 MB
  short8* PWlo = PWhi + (size_t)HH * HH / 8;          // 8 MB
  short* SAh = (short*)(PWlo + (size_t)HH * HH / 8);  // 256 KB each
  short* SAl = SAh + BH;
  short* SBh = SAl + BH;
  short* SBl = SBh + BH;

  pack_what<<<8192, 64, 0, stream>>>(What, PWhi, PWlo);
  prep_state<<<512, 256, 0, stream>>>(s0, SAh, SAl);
  ugemm<<<dim3(256, 32), 256, 0, stream>>>(x, Win, out);

  for (int t = 0; t < TT; ++t) {
    const short* curH = (t & 1) ? SBh : SAh;
    const short* curL = (t & 1) ? SBl : SAl;
    short* nxtH = (t & 1) ? SAh : SBh;
    short* nxtL = (t & 1) ? SAl : SBl;
    step_kernel<<<256, 1024, 0, stream>>>(PWhi, PWlo, curH, curL, nxtH, nxtL,
                                          out + (size_t)t * BH);
  }
}